// Round 7
// baseline (302.993 us; speedup 1.0000x reference)
//
#include <hip/hip_runtime.h>
#include <math.h>

#define PRE_NMS 2000
#define POST_NMS 1000
#define IOU_T 0.7f
#define IMGSZ 800.0f
#define CAP 6144            // level-1 candidates per image (expected ~3600)
#define SORTN 2048          // level-2 refined candidates (expected ~2003)
#define NBINS 1024
#define NWORDS 32           // ceil(PRE_NMS/64)
#define NSLICE 16           // hist blocks per image
#define NSLICE2 4           // compact blocks per image (1024 threads each)
#define MROWS 2048          // padded row dim of transposed mask

typedef unsigned long long u64;

__device__ __forceinline__ unsigned key_of(float f) {
    unsigned u = __float_as_uint(f);
    return (u & 0x80000000u) ? ~u : (u | 0x80000000u);
}
__device__ __forceinline__ float inv_key(unsigned k) {
    unsigned u = (k & 0x80000000u) ? (k ^ 0x80000000u) : ~k;
    return __uint_as_float(u);
}

// ---- K1: 10-bit histogram, 16 slices/image; LAST block per image does the
// suffix scan and writes T1[b] (device-fence + done-counter handshake).
__global__ __launch_bounds__(256) void hist_thresh_kernel(
    const float* __restrict__ scores, int A, unsigned* __restrict__ ghist,
    int* __restrict__ done, int* __restrict__ T1) {
  int b = blockIdx.x, slice = blockIdx.y;
  __shared__ unsigned sa[2][NBINS];   // sa[0] doubles as block-local hist
  __shared__ int s_last;
  int tid = threadIdx.x;
  for (int i = tid; i < NBINS; i += 256) sa[0][i] = 0;
  __syncthreads();
  int per = (A + NSLICE - 1) / NSLICE;
  int lo = slice * per, hi = min(lo + per, A);
  const float* sc = scores + (size_t)b * A;
  for (int i = lo + tid; i < hi; i += 256)
    atomicAdd(&sa[0][key_of(sc[i]) >> 22], 1u);
  __syncthreads();
  for (int i = tid; i < NBINS; i += 256)
    if (sa[0][i]) atomicAdd(&ghist[b * NBINS + i], sa[0][i]);
  __threadfence();                       // make ghist adds device-visible
  if (tid == 0) s_last = (atomicAdd(&done[b], 1) == NSLICE - 1);
  __syncthreads();
  if (!s_last) return;
  __threadfence();                       // acquire
  // last block: suffix-scan ghist[b] (ping-pong, 10 steps, 4 bins/thread)
  for (int i = tid; i < NBINS; i += 256) sa[0][i] = ghist[b * NBINS + i];
  __syncthreads();
  int src = 0;
  for (int d = 1; d < NBINS; d <<= 1) {
    for (int i = tid; i < NBINS; i += 256)
      sa[src ^ 1][i] = sa[src][i] + ((i + d < NBINS) ? sa[src][i + d] : 0u);
    __syncthreads();
    src ^= 1;
  }
  for (int i = tid; i < NBINS; i += 256) {
    unsigned v = sa[src][i];
    unsigned nx = (i < NBINS - 1) ? sa[src][i + 1] : 0u;
    if (v >= PRE_NMS && nx < PRE_NMS) T1[b] = i;
  }
}

// ---- K2: compact (4 x 1024-thread slices/image, 1 atomic/block) + LAST
// block per image runs refine + bitonic sort 2048 + fused decode.
__global__ __launch_bounds__(1024) void compact_refine_kernel(
    const float* __restrict__ scores, int A, const int* __restrict__ T1,
    u64* __restrict__ cand, int* __restrict__ cand_cnt, int* __restrict__ done2,
    const float* __restrict__ deltas, const float* __restrict__ anchors,
    float* __restrict__ boxes, float* __restrict__ topk_logit) {
  int b = blockIdx.x, slice = blockIdx.y;
  int tid = threadIdx.x;
  int lane = tid & 63, wave = tid >> 6;       // 16 waves
  int T = T1[b];
  int per = (A + NSLICE2 - 1) / NSLICE2;
  int lo = slice * per, hi = min(lo + per, A);
  const float* sc = scores + (size_t)b * A;
  // phase 1: count
  int cnt = 0;
  for (int i = lo + tid; i < hi; i += 1024)
    cnt += ((int)(key_of(sc[i]) >> 22) >= T);
  int pfx = cnt;
  #pragma unroll
  for (int d = 1; d < 64; d <<= 1) {
    int t2 = __shfl_up(pfx, d, 64);
    if (lane >= d) pfx += t2;
  }
  __shared__ int s_wt[16];
  __shared__ int s_base;
  __shared__ int s_last;
  if (lane == 63) s_wt[wave] = pfx;
  __syncthreads();
  if (tid == 0) {
    int acc = 0;
    #pragma unroll
    for (int w2 = 0; w2 < 16; ++w2) { int t3 = s_wt[w2]; s_wt[w2] = acc; acc += t3; }
    s_base = atomicAdd(&cand_cnt[b], acc);
  }
  __syncthreads();
  int my_off = s_base + s_wt[wave] + (pfx - cnt);
  u64* cb = cand + (size_t)b * CAP;
  for (int i = lo + tid; i < hi; i += 1024) {
    unsigned k = key_of(sc[i]);
    if ((int)(k >> 22) >= T) {
      if (my_off < CAP) cb[my_off] = ((u64)k << 32) | (unsigned)(~i);
      my_off++;
    }
  }
  __threadfence();
  if (tid == 0) s_last = (atomicAdd(&done2[b], 1) == NSLICE2 - 1);
  __syncthreads();
  if (!s_last) return;
  __threadfence();                       // acquire: all slices' cand visible
  // ---- refine (20-bit threshold) + sort + decode, 1024 threads ----
  __shared__ unsigned h2[NBINS];
  __shared__ unsigned tmp[NBINS];
  __shared__ u64 s[SORTN];
  __shared__ int s_above, s_sel, s_T2;
  int n = min(cand_cnt[b], CAP);
  h2[tid] = 0;
  if (tid == 0) { s_above = 0; s_sel = 0; }
  __syncthreads();
  int loc = 0;
  for (int i = tid; i < n; i += 1024) {
    unsigned k = (unsigned)(cb[i] >> 32);
    if ((int)(k >> 22) > T) loc++;
    else atomicAdd(&h2[(k >> 12) & 1023], 1u);
  }
  for (int d = 32; d; d >>= 1) loc += __shfl_down(loc, d, 64);
  if (lane == 0 && loc) atomicAdd(&s_above, loc);
  __syncthreads();
  unsigned v = h2[tid];
  for (int d = 1; d < NBINS; d <<= 1) {
    tmp[tid] = v;
    __syncthreads();
    if (tid + d < NBINS) v += tmp[tid + d];
    __syncthreads();
  }
  tmp[tid] = v;
  __syncthreads();
  int above = s_above;
  unsigned nextv = (tid < NBINS - 1) ? tmp[tid + 1] : 0u;
  if (above + (int)v >= PRE_NMS && above + (int)nextv < PRE_NMS) s_T2 = tid;
  __syncthreads();
  unsigned thresh20 = ((unsigned)T << 10) | (unsigned)s_T2;
  for (int i = tid; i < SORTN; i += 1024) s[i] = 0ULL;
  __syncthreads();
  for (int i = tid; i < n; i += 1024) {
    u64 cv = cb[i];
    if ((unsigned)(cv >> 44) >= thresh20) {
      int pos = atomicAdd(&s_sel, 1);
      if (pos < SORTN) s[pos] = cv;
    }
  }
  __syncthreads();
  for (int k = 2; k <= SORTN; k <<= 1) {
    for (int j = k >> 1; j > 0; j >>= 1) {
      for (int i = tid; i < SORTN; i += 1024) {
        int l = i ^ j;
        if (l > i) {
          u64 a = s[i], c2 = s[l];
          bool desc = ((i & k) == 0);
          if (desc ? (a < c2) : (a > c2)) { s[i] = c2; s[l] = a; }
        }
      }
      __syncthreads();
    }
  }
  // fused decode (non-contracted fp32, matches numpy op-by-op)
  const float CLIP = 4.135166556742356f;  // log(1000/16)
  for (int i = tid; i < PRE_NMS; i += 1024) {
    u64 v2 = s[i];
    int a = (int)(~(unsigned)v2);
    topk_logit[b * PRE_NMS + i] = inv_key((unsigned)(v2 >> 32));
    float4 dl = ((const float4*)deltas)[(size_t)b * A + a];
    float4 an = ((const float4*)anchors)[a];
    float wa = __fsub_rn(an.z, an.x);
    float ha = __fsub_rn(an.w, an.y);
    float cxa = __fadd_rn(an.x, __fmul_rn(0.5f, wa));
    float cya = __fadd_rn(an.y, __fmul_rn(0.5f, ha));
    float dw = fminf(dl.z, CLIP), dh = fminf(dl.w, CLIP);
    float cx = __fadd_rn(__fmul_rn(dl.x, wa), cxa);
    float cy = __fadd_rn(__fmul_rn(dl.y, ha), cya);
    float w2 = __fmul_rn((float)exp((double)dw), wa);
    float h2f = __fmul_rn((float)exp((double)dh), ha);
    float x1 = __fsub_rn(cx, __fmul_rn(0.5f, w2));
    float y1 = __fsub_rn(cy, __fmul_rn(0.5f, h2f));
    float x2 = __fadd_rn(cx, __fmul_rn(0.5f, w2));
    float y2 = __fadd_rn(cy, __fmul_rn(0.5f, h2f));
    x1 = fminf(fmaxf(x1, 0.f), IMGSZ);
    y1 = fminf(fmaxf(y1, 0.f), IMGSZ);
    x2 = fminf(fmaxf(x2, 0.f), IMGSZ);
    y2 = fminf(fmaxf(y2, 0.f), IMGSZ);
    ((float4*)boxes)[(size_t)b * PRE_NMS + i] = make_float4(x1, y1, x2, y2);
  }
}

// ---- K3: IoU tiles, one wave per 64x64 upper-triangle tile ----------------
__global__ __launch_bounds__(64) void iou_tile(
    const float* __restrict__ boxes, u64* __restrict__ maskT) {
  int k = blockIdx.x;       // 0..527 -> (ti <= wj) pair
  int b = blockIdx.y;
  int wj = (int)((sqrtf(8.0f * k + 1.0f) - 1.0f) * 0.5f);
  while ((wj + 1) * (wj + 2) / 2 <= k) ++wj;
  while (wj * (wj + 1) / 2 > k) --wj;
  int ti = k - wj * (wj + 1) / 2;
  int lane = threadIdx.x;
  int i = ti * 64 + lane;
  const float4* bb = (const float4*)boxes + (size_t)b * PRE_NMS;
  __shared__ float4 sbox[64];
  int jg = wj * 64 + lane;
  sbox[lane] = bb[min(jg, PRE_NMS - 1)];
  float4 A4 = bb[min(i, PRE_NMS - 1)];
  __syncthreads();
  float area_a = __fmul_rn(__fsub_rn(A4.z, A4.x), __fsub_rn(A4.w, A4.y));
  u64 m = 0;
  #pragma unroll 8
  for (int jj = 0; jj < 64; ++jj) {
    float4 Bb = sbox[jj];                  // uniform address -> broadcast
    float area_b = __fmul_rn(__fsub_rn(Bb.z, Bb.x), __fsub_rn(Bb.w, Bb.y));
    float ltx = fmaxf(A4.x, Bb.x), lty = fmaxf(A4.y, Bb.y);
    float rbx = fminf(A4.z, Bb.z), rby = fminf(A4.w, Bb.w);
    float iw = fmaxf(__fsub_rn(rbx, ltx), 0.f);
    float ih = fmaxf(__fsub_rn(rby, lty), 0.f);
    float inter = __fmul_rn(iw, ih);
    float denom = __fadd_rn(__fsub_rn(__fadd_rn(area_a, area_b), inter), 1e-9f);
    float iou = inter / denom;
    int j = wj * 64 + jj;
    if (j > i && iou > IOU_T) m |= 1ULL << jj;
  }
  maskT[((size_t)b * NWORDS + wj) * MROWS + i] = m;   // coalesced
}

// ---- K4: NMS scan v6 — lane-distributed diagonal + readlane SALU chain ----
// Phase 1: lane bb of wave 0 holds diag word bb (1 VGPR); the 64-step serial
// resolve runs on readlane-produced SGPRs -> pure scalar ALU, no memory on
// the critical path. No register arrays for the allocator to break.
#define WSTRIDE 65
__global__ __launch_bounds__(256, 1) void nms_scan(
    const u64* __restrict__ maskT, const float* __restrict__ boxes,
    const float* __restrict__ logits, float* __restrict__ out) {
  int b = blockIdx.x;
  int tid = threadIdx.x;
  int wave = tid >> 6, lane = tid & 63;
  __shared__ u64 buf[2][NWORDS * WSTRIDE];   // 2 x 16.25 KiB
  __shared__ u64 s_keep[NWORDS];
  __shared__ u64 s_cur;
  if (tid < NWORDS) s_keep[tid] = (tid == NWORDS - 1) ? 0xFFFFULL : ~0ULL;
  const u64* mb = maskT + (size_t)b * NWORDS * MROWS;
  int w = tid >> 3;          // word 0..31
  int sub = tid & 7;         // rows sub*8 .. sub*8+7 of the chunk
  uint4 cur0, cur1, cur2, cur3, nx0, nx1, nx2, nx3;
  {
    const uint4* src = (const uint4*)(mb + (size_t)w * MROWS + sub * 8);
    cur0 = src[0]; cur1 = src[1]; cur2 = src[2]; cur3 = src[3];
  }
  for (int c = 0; c < NWORDS; ++c) {
    int p = c & 1;
    if (w >= c) {                        // only upper-triangle words are used
      u64* dst = &buf[p][w * WSTRIDE + sub * 8];
      dst[0] = ((u64)cur0.y << 32) | cur0.x;  dst[1] = ((u64)cur0.w << 32) | cur0.z;
      dst[2] = ((u64)cur1.y << 32) | cur1.x;  dst[3] = ((u64)cur1.w << 32) | cur1.z;
      dst[4] = ((u64)cur2.y << 32) | cur2.x;  dst[5] = ((u64)cur2.w << 32) | cur2.z;
      dst[6] = ((u64)cur3.y << 32) | cur3.x;  dst[7] = ((u64)cur3.w << 32) | cur3.z;
    }
    __syncthreads();                     // barrier 1: chunk visible in buf[p]
    if (c + 1 < NWORDS && w >= c + 1) {  // prefetch next chunk (vmcnt overlaps)
      const uint4* src = (const uint4*)(mb + (size_t)w * MROWS + (c + 1) * 64 + sub * 8);
      nx0 = src[0]; nx1 = src[1]; nx2 = src[2]; nx3 = src[3];
    }
    // phase 1: serial diagonal resolve on scalar pipe
    if (wave == 0) {
      u64 diag = buf[p][c * WSTRIDE + lane];   // lane bb holds row bb's diag word
      unsigned dlo = (unsigned)diag, dhi = (unsigned)(diag >> 32);
      u64 k0 = s_keep[c];
      unsigned clo = __builtin_amdgcn_readfirstlane((unsigned)k0);
      unsigned chi = __builtin_amdgcn_readfirstlane((unsigned)(k0 >> 32));
      #pragma unroll
      for (int bb = 0; bb < 32; ++bb) {
        unsigned rlo = __builtin_amdgcn_readlane(dlo, bb);
        unsigned rhi = __builtin_amdgcn_readlane(dhi, bb);
        unsigned msk = 0u - ((clo >> bb) & 1u);
        clo &= ~(rlo & msk);
        chi &= ~(rhi & msk);
      }
      #pragma unroll
      for (int bb = 0; bb < 32; ++bb) {
        unsigned rlo = __builtin_amdgcn_readlane(dlo, bb + 32);
        unsigned rhi = __builtin_amdgcn_readlane(dhi, bb + 32);
        unsigned msk = 0u - ((chi >> bb) & 1u);
        clo &= ~(rlo & msk);
        chi &= ~(rhi & msk);
      }
      u64 cur = ((u64)chi << 32) | clo;
      if (lane == 0) { s_keep[c] = cur; s_cur = cur; }
    }
    __syncthreads();                     // barrier 2: s_cur visible
    // phase 2: words w > c, lane l owns word l (half-wave row split)
    {
      u64 cur = s_cur;
      int l = lane & 31;
      int h = lane >> 5;
      if (l > c) {
        u64 v = 0;
        int base_bb = wave * 16 + h * 8;
        #pragma unroll
        for (int kk = 0; kk < 8; ++kk) {
          int bbr = base_bb + kk;
          u64 bit = (cur >> bbr) & 1ULL;
          v |= buf[p][l * WSTRIDE + bbr] & (0ULL - bit);
        }
        v |= __shfl_xor(v, 32, 64);
        if (lane < 32 && v) atomicAnd(&s_keep[l], ~v);
      }
    }
    cur0 = nx0; cur1 = nx1; cur2 = nx2; cur3 = nx3;
  }
  __syncthreads();
  // fused emit: rank kept boxes, write [box, sigmoid]
  __shared__ int pre[NWORDS];
  if (tid == 0) {
    int acc = 0;
    for (int ww = 0; ww < NWORDS; ++ww) {
      pre[ww] = acc;
      acc += __popcll(s_keep[ww]);
    }
  }
  __syncthreads();
  const float* lg_b = logits + b * PRE_NMS;
  const float4* bx_b = (const float4*)boxes + (size_t)b * PRE_NMS;
  for (int i = tid; i < PRE_NMS; i += 256) {
    u64 wv = s_keep[i >> 6];
    if ((wv >> (i & 63)) & 1) {
      int rank = pre[i >> 6] + __popcll(wv & ((1ULL << (i & 63)) - 1ULL));
      if (rank < POST_NMS) {
        float4 bx = bx_b[i];
        float lg = lg_b[i];
        float e = (float)exp(-(double)lg);
        float pp = 1.0f / (1.0f + e);
        float* o = out + ((size_t)b * POST_NMS + rank) * 5;
        o[0] = bx.x; o[1] = bx.y; o[2] = bx.z; o[3] = bx.w; o[4] = pp;
      }
    }
  }
}

extern "C" void kernel_launch(void* const* d_in, const int* in_sizes, int n_in,
                              void* d_out, int out_size, void* d_ws, size_t ws_size,
                              hipStream_t stream) {
  const float* scores  = (const float*)d_in[0];
  const float* deltas  = (const float*)d_in[1];
  const float* anchors = (const float*)d_in[2];
  int A = in_sizes[2] / 4;          // 159882
  int B = in_sizes[0] / A;          // 16

  char* ws = (char*)d_ws;
  size_t off = 0;
  auto alloc = [&](size_t bytes) {
    void* p = ws + off;
    off += (bytes + 255) & ~(size_t)255;
    return p;
  };
  // zeroed region: ghist | cand_cnt | done | done2
  unsigned* ghist    = (unsigned*)alloc((size_t)B * NBINS * 4);
  int*      cand_cnt = (int*)alloc((size_t)B * 4);
  int*      done     = (int*)alloc((size_t)B * 4);
  int*      done2    = (int*)alloc((size_t)B * 4);
  size_t zero_bytes = off;
  int*      T1       = (int*)alloc((size_t)B * 4);
  u64*      cand     = (u64*)alloc((size_t)B * CAP * 8);
  float*    topk_lg  = (float*)alloc((size_t)B * PRE_NMS * 4);
  float*    boxes    = (float*)alloc((size_t)B * PRE_NMS * 16);
  u64*      maskT    = (u64*)alloc((size_t)B * NWORDS * MROWS * 8);

  hipMemsetAsync(d_out, 0, (size_t)out_size * 4, stream);
  hipMemsetAsync(ws, 0, zero_bytes, stream);

  hist_thresh_kernel<<<dim3(B, NSLICE), 256, 0, stream>>>(scores, A, ghist, done, T1);
  compact_refine_kernel<<<dim3(B, NSLICE2), 1024, 0, stream>>>(
      scores, A, T1, cand, cand_cnt, done2, deltas, anchors, boxes, topk_lg);
  int ntiles = NWORDS * (NWORDS + 1) / 2;   // 528 upper-triangle tiles
  iou_tile<<<dim3(ntiles, B), 64, 0, stream>>>(boxes, maskT);
  nms_scan<<<B, 256, 0, stream>>>(maskT, boxes, topk_lg, (float*)d_out);
}

// Round 8
// 258.959 us; speedup vs baseline: 1.1700x; 1.1700x over previous
//
#include <hip/hip_runtime.h>
#include <math.h>

#define PRE_NMS 2000
#define POST_NMS 1000
#define IOU_T 0.7f
#define IMGSZ 800.0f
#define CAP 6144            // level-1 candidates per image (expected ~3600)
#define SORTN 2048          // level-2 refined candidates (expected ~2003)
#define NBINS 1024
#define NWORDS 32           // ceil(PRE_NMS/64)
#define NSLICE 16           // blocks per image for hist/compact
#define MROWS 2048          // padded row dim of transposed mask

typedef unsigned long long u64;

__device__ __forceinline__ unsigned key_of(float f) {
    unsigned u = __float_as_uint(f);
    return (u & 0x80000000u) ? ~u : (u | 0x80000000u);
}
__device__ __forceinline__ float inv_key(unsigned k) {
    unsigned u = (k & 0x80000000u) ? (k ^ 0x80000000u) : ~k;
    return __uint_as_float(u);
}

// ---- K1: level-1 histogram (10-bit), 16 slices/image --------------------
__global__ __launch_bounds__(256) void hist_kernel(
    const float* __restrict__ scores, int A, unsigned* __restrict__ ghist) {
  int b = blockIdx.x, slice = blockIdx.y;
  __shared__ unsigned h[NBINS];
  int tid = threadIdx.x;
  for (int i = tid; i < NBINS; i += 256) h[i] = 0;
  __syncthreads();
  int per = (A + NSLICE - 1) / NSLICE;
  int lo = slice * per, hi = min(lo + per, A);
  const float* sc = scores + (size_t)b * A;
  for (int i = lo + tid; i < hi; i += 256)
    atomicAdd(&h[key_of(sc[i]) >> 22], 1u);
  __syncthreads();
  for (int i = tid; i < NBINS; i += 256)
    if (h[i]) atomicAdd(&ghist[b * NBINS + i], h[i]);
}

// ---- K2: suffix-scan ghist, find level-1 threshold bin T1 ----------------
__global__ __launch_bounds__(1024) void thresh1_kernel(
    const unsigned* __restrict__ ghist, int* __restrict__ T1) {
  int b = blockIdx.x, tid = threadIdx.x;
  __shared__ unsigned tmp[NBINS];
  __shared__ int s_T;
  unsigned v = ghist[b * NBINS + tid];
  for (int d = 1; d < NBINS; d <<= 1) {
    tmp[tid] = v;
    __syncthreads();
    if (tid + d < NBINS) v += tmp[tid + d];
    __syncthreads();
  }
  tmp[tid] = v;   // count of keys with bin >= tid
  __syncthreads();
  unsigned nextv = (tid < NBINS - 1) ? tmp[tid + 1] : 0u;
  if (v >= PRE_NMS && nextv < PRE_NMS) s_T = tid;
  __syncthreads();
  if (tid == 0) T1[b] = s_T;
}

// ---- K3: compact candidates above T1 (two-phase, 1 atomic/block) ---------
__global__ __launch_bounds__(256) void compact_kernel(
    const float* __restrict__ scores, int A, const int* __restrict__ T1,
    u64* __restrict__ cand, int* __restrict__ cand_cnt) {
  int b = blockIdx.x, slice = blockIdx.y;
  int tid = threadIdx.x;
  int lane = tid & 63, wave = tid >> 6;
  int T = T1[b];
  int per = (A + NSLICE - 1) / NSLICE;
  int lo = slice * per, hi = min(lo + per, A);
  const float* sc = scores + (size_t)b * A;
  int cnt = 0;
  for (int i = lo + tid; i < hi; i += 256)
    cnt += ((int)(key_of(sc[i]) >> 22) >= T);
  int pfx = cnt;
  #pragma unroll
  for (int d = 1; d < 64; d <<= 1) {
    int t2 = __shfl_up(pfx, d, 64);
    if (lane >= d) pfx += t2;
  }
  __shared__ int s_wt[4];
  __shared__ int s_base;
  if (lane == 63) s_wt[wave] = pfx;
  __syncthreads();
  if (tid == 0) {
    int tot = s_wt[0] + s_wt[1] + s_wt[2] + s_wt[3];
    int acc = 0;
    #pragma unroll
    for (int w2 = 0; w2 < 4; ++w2) { int t3 = s_wt[w2]; s_wt[w2] = acc; acc += t3; }
    s_base = atomicAdd(&cand_cnt[b], tot);
  }
  __syncthreads();
  int my_off = s_base + s_wt[wave] + (pfx - cnt);
  u64* cb = cand + (size_t)b * CAP;
  for (int i = lo + tid; i < hi; i += 256) {
    unsigned k = key_of(sc[i]);
    if ((int)(k >> 22) >= T) {
      if (my_off < CAP) cb[my_off] = ((u64)k << 32) | (unsigned)(~i);
      my_off++;
    }
  }
}

// ---- K4: 20-bit threshold refinement, select ~2000-2048 cands (unsorted) --
__global__ __launch_bounds__(1024) void refine_select_kernel(
    const u64* __restrict__ cand, const int* __restrict__ cand_cnt,
    const int* __restrict__ T1,
    u64* __restrict__ gsel, int* __restrict__ sel_cnt) {
  int b = blockIdx.x, tid = threadIdx.x;
  int lane = tid & 63;
  __shared__ unsigned h2[NBINS];
  __shared__ unsigned tmp[NBINS];
  __shared__ int s_above, s_sel, s_T2;
  int n = min(cand_cnt[b], CAP);
  const u64* cb = cand + (size_t)b * CAP;
  h2[tid] = 0;
  if (tid == 0) { s_above = 0; s_sel = 0; }
  __syncthreads();
  int T1v = T1[b];
  int loc = 0;
  for (int i = tid; i < n; i += 1024) {
    unsigned k = (unsigned)(cb[i] >> 32);
    if ((int)(k >> 22) > T1v) loc++;
    else atomicAdd(&h2[(k >> 12) & 1023], 1u);
  }
  for (int d = 32; d; d >>= 1) loc += __shfl_down(loc, d, 64);
  if (lane == 0 && loc) atomicAdd(&s_above, loc);
  __syncthreads();
  unsigned v = h2[tid];
  for (int d = 1; d < NBINS; d <<= 1) {
    tmp[tid] = v;
    __syncthreads();
    if (tid + d < NBINS) v += tmp[tid + d];
    __syncthreads();
  }
  tmp[tid] = v;
  __syncthreads();
  int above = s_above;
  unsigned nextv = (tid < NBINS - 1) ? tmp[tid + 1] : 0u;
  if (above + (int)v >= PRE_NMS && above + (int)nextv < PRE_NMS) s_T2 = tid;
  __syncthreads();
  unsigned thresh20 = ((unsigned)T1v << 10) | (unsigned)s_T2;
  u64* gs = gsel + (size_t)b * SORTN;
  for (int i = tid; i < n; i += 1024) {
    u64 cv = cb[i];
    if ((unsigned)(cv >> 44) >= thresh20) {
      int pos = atomicAdd(&s_sel, 1);
      if (pos < SORTN) gs[pos] = cv;
    }
  }
  __syncthreads();
  if (tid == 0) sel_cnt[b] = min(s_sel, SORTN);
}

// ---- K5: parallel rank-count (replaces bitonic sort) + fused decode -------
// rank(i) = #{j : key_j > key_i}; keys unique -> ranks a permutation.
// 8 blocks/image x 256 thr; keys LDS-staged, broadcast ulonglong2 reads.
__global__ __launch_bounds__(256) void rank_decode_kernel(
    const u64* __restrict__ gsel, const int* __restrict__ sel_cnt,
    const float* __restrict__ deltas, const float* __restrict__ anchors, int A,
    float* __restrict__ boxes, float* __restrict__ topk_logit) {
  int b = blockIdx.x, ci = blockIdx.y;
  int tid = threadIdx.x;
  __shared__ u64 keys[SORTN];   // 16 KiB
  const u64* gs = gsel + (size_t)b * SORTN;
  int n = sel_cnt[b];           // in [2000, 2048]
  for (int i = tid; i < SORTN; i += 256)
    keys[i] = (i < n) ? gs[i] : 0ULL;
  __syncthreads();
  int i = ci * 256 + tid;
  u64 my = keys[i];
  int rank = 0;
  const ulonglong2* k2 = (const ulonglong2*)keys;
  #pragma unroll 4
  for (int j = 0; j < SORTN / 2; ++j) {
    ulonglong2 kk = k2[j];                 // uniform addr -> LDS broadcast
    rank += (kk.x > my) + (kk.y > my);
  }
  if (i < n && rank < PRE_NMS) {
    int a = (int)(~(unsigned)my);
    topk_logit[b * PRE_NMS + rank] = inv_key((unsigned)(my >> 32));
    const float CLIP = 4.135166556742356f;  // log(1000/16)
    float4 dl = ((const float4*)deltas)[(size_t)b * A + a];
    float4 an = ((const float4*)anchors)[a];
    float wa = __fsub_rn(an.z, an.x);
    float ha = __fsub_rn(an.w, an.y);
    float cxa = __fadd_rn(an.x, __fmul_rn(0.5f, wa));
    float cya = __fadd_rn(an.y, __fmul_rn(0.5f, ha));
    float dw = fminf(dl.z, CLIP), dh = fminf(dl.w, CLIP);
    float cx = __fadd_rn(__fmul_rn(dl.x, wa), cxa);
    float cy = __fadd_rn(__fmul_rn(dl.y, ha), cya);
    float w2 = __fmul_rn((float)exp((double)dw), wa);
    float h2f = __fmul_rn((float)exp((double)dh), ha);
    float x1 = __fsub_rn(cx, __fmul_rn(0.5f, w2));
    float y1 = __fsub_rn(cy, __fmul_rn(0.5f, h2f));
    float x2 = __fadd_rn(cx, __fmul_rn(0.5f, w2));
    float y2 = __fadd_rn(cy, __fmul_rn(0.5f, h2f));
    x1 = fminf(fmaxf(x1, 0.f), IMGSZ);
    y1 = fminf(fmaxf(y1, 0.f), IMGSZ);
    x2 = fminf(fmaxf(x2, 0.f), IMGSZ);
    y2 = fminf(fmaxf(y2, 0.f), IMGSZ);
    ((float4*)boxes)[(size_t)b * PRE_NMS + rank] = make_float4(x1, y1, x2, y2);
  }
}

// ---- K6: IoU tiles, one wave per 64x64 upper-triangle tile ----------------
__global__ __launch_bounds__(64) void iou_tile(
    const float* __restrict__ boxes, u64* __restrict__ maskT) {
  int k = blockIdx.x;       // 0..527 -> (ti <= wj) pair
  int b = blockIdx.y;
  int wj = (int)((sqrtf(8.0f * k + 1.0f) - 1.0f) * 0.5f);
  while ((wj + 1) * (wj + 2) / 2 <= k) ++wj;
  while (wj * (wj + 1) / 2 > k) --wj;
  int ti = k - wj * (wj + 1) / 2;
  int lane = threadIdx.x;
  int i = ti * 64 + lane;
  const float4* bb = (const float4*)boxes + (size_t)b * PRE_NMS;
  __shared__ float4 sbox[64];
  int jg = wj * 64 + lane;
  sbox[lane] = bb[min(jg, PRE_NMS - 1)];
  float4 A4 = bb[min(i, PRE_NMS - 1)];
  __syncthreads();
  float area_a = __fmul_rn(__fsub_rn(A4.z, A4.x), __fsub_rn(A4.w, A4.y));
  u64 m = 0;
  #pragma unroll 8
  for (int jj = 0; jj < 64; ++jj) {
    float4 Bb = sbox[jj];                  // uniform address -> broadcast
    float area_b = __fmul_rn(__fsub_rn(Bb.z, Bb.x), __fsub_rn(Bb.w, Bb.y));
    float ltx = fmaxf(A4.x, Bb.x), lty = fmaxf(A4.y, Bb.y);
    float rbx = fminf(A4.z, Bb.z), rby = fminf(A4.w, Bb.w);
    float iw = fmaxf(__fsub_rn(rbx, ltx), 0.f);
    float ih = fmaxf(__fsub_rn(rby, lty), 0.f);
    float inter = __fmul_rn(iw, ih);
    float denom = __fadd_rn(__fsub_rn(__fadd_rn(area_a, area_b), inter), 1e-9f);
    float iou = inter / denom;
    int j = wj * 64 + jj;
    if (j > i && iou > IOU_T) m |= 1ULL << jj;
  }
  maskT[((size_t)b * NWORDS + wj) * MROWS + i] = m;   // coalesced
}

// ---- K7: NMS scan v6 — lane-distributed diagonal + readlane SALU chain ----
#define WSTRIDE 65
__global__ __launch_bounds__(256, 1) void nms_scan(
    const u64* __restrict__ maskT, const float* __restrict__ boxes,
    const float* __restrict__ logits, float* __restrict__ out) {
  int b = blockIdx.x;
  int tid = threadIdx.x;
  int wave = tid >> 6, lane = tid & 63;
  __shared__ u64 buf[2][NWORDS * WSTRIDE];   // 2 x 16.25 KiB
  __shared__ u64 s_keep[NWORDS];
  __shared__ u64 s_cur;
  if (tid < NWORDS) s_keep[tid] = (tid == NWORDS - 1) ? 0xFFFFULL : ~0ULL;
  const u64* mb = maskT + (size_t)b * NWORDS * MROWS;
  int w = tid >> 3;          // word 0..31
  int sub = tid & 7;         // rows sub*8 .. sub*8+7 of the chunk
  uint4 cur0, cur1, cur2, cur3, nx0, nx1, nx2, nx3;
  {
    const uint4* src = (const uint4*)(mb + (size_t)w * MROWS + sub * 8);
    cur0 = src[0]; cur1 = src[1]; cur2 = src[2]; cur3 = src[3];
  }
  for (int c = 0; c < NWORDS; ++c) {
    int p = c & 1;
    if (w >= c) {                        // only upper-triangle words are used
      u64* dst = &buf[p][w * WSTRIDE + sub * 8];
      dst[0] = ((u64)cur0.y << 32) | cur0.x;  dst[1] = ((u64)cur0.w << 32) | cur0.z;
      dst[2] = ((u64)cur1.y << 32) | cur1.x;  dst[3] = ((u64)cur1.w << 32) | cur1.z;
      dst[4] = ((u64)cur2.y << 32) | cur2.x;  dst[5] = ((u64)cur2.w << 32) | cur2.z;
      dst[6] = ((u64)cur3.y << 32) | cur3.x;  dst[7] = ((u64)cur3.w << 32) | cur3.z;
    }
    __syncthreads();                     // barrier 1: chunk visible in buf[p]
    if (c + 1 < NWORDS && w >= c + 1) {  // prefetch next chunk (vmcnt overlaps)
      const uint4* src = (const uint4*)(mb + (size_t)w * MROWS + (c + 1) * 64 + sub * 8);
      nx0 = src[0]; nx1 = src[1]; nx2 = src[2]; nx3 = src[3];
    }
    // phase 1: serial diagonal resolve on scalar pipe
    if (wave == 0) {
      u64 diag = buf[p][c * WSTRIDE + lane];   // lane bb holds row bb's diag word
      unsigned dlo = (unsigned)diag, dhi = (unsigned)(diag >> 32);
      u64 k0 = s_keep[c];
      unsigned clo = __builtin_amdgcn_readfirstlane((unsigned)k0);
      unsigned chi = __builtin_amdgcn_readfirstlane((unsigned)(k0 >> 32));
      #pragma unroll
      for (int bb = 0; bb < 32; ++bb) {
        unsigned rlo = __builtin_amdgcn_readlane(dlo, bb);
        unsigned rhi = __builtin_amdgcn_readlane(dhi, bb);
        unsigned msk = 0u - ((clo >> bb) & 1u);
        clo &= ~(rlo & msk);
        chi &= ~(rhi & msk);
      }
      #pragma unroll
      for (int bb = 0; bb < 32; ++bb) {
        unsigned rlo = __builtin_amdgcn_readlane(dlo, bb + 32);
        unsigned rhi = __builtin_amdgcn_readlane(dhi, bb + 32);
        unsigned msk = 0u - ((chi >> bb) & 1u);
        clo &= ~(rlo & msk);
        chi &= ~(rhi & msk);
      }
      u64 cur = ((u64)chi << 32) | clo;
      if (lane == 0) { s_keep[c] = cur; s_cur = cur; }
    }
    __syncthreads();                     // barrier 2: s_cur visible
    // phase 2: words w > c, lane l owns word l (half-wave row split)
    {
      u64 cur = s_cur;
      int l = lane & 31;
      int h = lane >> 5;
      if (l > c) {
        u64 v = 0;
        int base_bb = wave * 16 + h * 8;
        #pragma unroll
        for (int kk = 0; kk < 8; ++kk) {
          int bbr = base_bb + kk;
          u64 bit = (cur >> bbr) & 1ULL;
          v |= buf[p][l * WSTRIDE + bbr] & (0ULL - bit);
        }
        v |= __shfl_xor(v, 32, 64);
        if (lane < 32 && v) atomicAnd(&s_keep[l], ~v);
      }
    }
    cur0 = nx0; cur1 = nx1; cur2 = nx2; cur3 = nx3;
  }
  __syncthreads();
  // fused emit: rank kept boxes, write [box, sigmoid]
  __shared__ int pre[NWORDS];
  if (tid == 0) {
    int acc = 0;
    for (int ww = 0; ww < NWORDS; ++ww) {
      pre[ww] = acc;
      acc += __popcll(s_keep[ww]);
    }
  }
  __syncthreads();
  const float* lg_b = logits + b * PRE_NMS;
  const float4* bx_b = (const float4*)boxes + (size_t)b * PRE_NMS;
  for (int i = tid; i < PRE_NMS; i += 256) {
    u64 wv = s_keep[i >> 6];
    if ((wv >> (i & 63)) & 1) {
      int rank = pre[i >> 6] + __popcll(wv & ((1ULL << (i & 63)) - 1ULL));
      if (rank < POST_NMS) {
        float4 bx = bx_b[i];
        float lg = lg_b[i];
        float e = (float)exp(-(double)lg);
        float pp = 1.0f / (1.0f + e);
        float* o = out + ((size_t)b * POST_NMS + rank) * 5;
        o[0] = bx.x; o[1] = bx.y; o[2] = bx.z; o[3] = bx.w; o[4] = pp;
      }
    }
  }
}

extern "C" void kernel_launch(void* const* d_in, const int* in_sizes, int n_in,
                              void* d_out, int out_size, void* d_ws, size_t ws_size,
                              hipStream_t stream) {
  const float* scores  = (const float*)d_in[0];
  const float* deltas  = (const float*)d_in[1];
  const float* anchors = (const float*)d_in[2];
  int A = in_sizes[2] / 4;          // 159882
  int B = in_sizes[0] / A;          // 16

  char* ws = (char*)d_ws;
  size_t off = 0;
  auto alloc = [&](size_t bytes) {
    void* p = ws + off;
    off += (bytes + 255) & ~(size_t)255;
    return p;
  };
  // zeroed region: ghist | cand_cnt
  unsigned* ghist    = (unsigned*)alloc((size_t)B * NBINS * 4);
  int*      cand_cnt = (int*)alloc((size_t)B * 4);
  size_t zero_bytes = off;
  int*      T1       = (int*)alloc((size_t)B * 4);
  u64*      cand     = (u64*)alloc((size_t)B * CAP * 8);
  u64*      gsel     = (u64*)alloc((size_t)B * SORTN * 8);
  int*      sel_cnt  = (int*)alloc((size_t)B * 4);
  float*    topk_lg  = (float*)alloc((size_t)B * PRE_NMS * 4);
  float*    boxes    = (float*)alloc((size_t)B * PRE_NMS * 16);
  u64*      maskT    = (u64*)alloc((size_t)B * NWORDS * MROWS * 8);

  hipMemsetAsync(d_out, 0, (size_t)out_size * 4, stream);
  hipMemsetAsync(ws, 0, zero_bytes, stream);

  hist_kernel<<<dim3(B, NSLICE), 256, 0, stream>>>(scores, A, ghist);
  thresh1_kernel<<<B, 1024, 0, stream>>>(ghist, T1);
  compact_kernel<<<dim3(B, NSLICE), 256, 0, stream>>>(scores, A, T1, cand, cand_cnt);
  refine_select_kernel<<<B, 1024, 0, stream>>>(cand, cand_cnt, T1, gsel, sel_cnt);
  rank_decode_kernel<<<dim3(B, SORTN / 256), 256, 0, stream>>>(
      gsel, sel_cnt, deltas, anchors, A, boxes, topk_lg);
  int ntiles = NWORDS * (NWORDS + 1) / 2;   // 528 upper-triangle tiles
  iou_tile<<<dim3(ntiles, B), 64, 0, stream>>>(boxes, maskT);
  nms_scan<<<B, 256, 0, stream>>>(maskT, boxes, topk_lg, (float*)d_out);
}

// Round 9
// 239.369 us; speedup vs baseline: 1.2658x; 1.0818x over previous
//
#include <hip/hip_runtime.h>
#include <math.h>

#define PRE_NMS 2000
#define POST_NMS 1000
#define IOU_T 0.7f
#define IMGSZ 800.0f
#define CAP 6144            // level-1 candidates per image (expected ~3600)
#define SORTN 2048          // level-2 refined candidates (expected ~2003)
#define NBINS 1024
#define NWORDS 32           // ceil(PRE_NMS/64)
#define NSLICE 16           // blocks per image for hist/compact
#define MROWS 2048          // padded row dim of transposed mask

typedef unsigned long long u64;

__device__ __forceinline__ unsigned key_of(float f) {
    unsigned u = __float_as_uint(f);
    return (u & 0x80000000u) ? ~u : (u | 0x80000000u);
}
__device__ __forceinline__ float inv_key(unsigned k) {
    unsigned u = (k & 0x80000000u) ? (k ^ 0x80000000u) : ~k;
    return __uint_as_float(u);
}

// ---- K1: level-1 histogram (10-bit), 16 slices/image --------------------
__global__ __launch_bounds__(256) void hist_kernel(
    const float* __restrict__ scores, int A, unsigned* __restrict__ ghist) {
  int b = blockIdx.x, slice = blockIdx.y;
  __shared__ unsigned h[NBINS];
  int tid = threadIdx.x;
  for (int i = tid; i < NBINS; i += 256) h[i] = 0;
  __syncthreads();
  int per = (A + NSLICE - 1) / NSLICE;
  int lo = slice * per, hi = min(lo + per, A);
  const float* sc = scores + (size_t)b * A;
  for (int i = lo + tid; i < hi; i += 256)
    atomicAdd(&h[key_of(sc[i]) >> 22], 1u);
  __syncthreads();
  for (int i = tid; i < NBINS; i += 256)
    if (h[i]) atomicAdd(&ghist[b * NBINS + i], h[i]);
}

// ---- K2: compact above T1; T1 computed in-block from ghist (thresh fold) --
__global__ __launch_bounds__(256) void compact_kernel(
    const float* __restrict__ scores, int A, const unsigned* __restrict__ ghist,
    u64* __restrict__ cand, int* __restrict__ cand_cnt, int* __restrict__ T1) {
  int b = blockIdx.x, slice = blockIdx.y;
  int tid = threadIdx.x;
  int lane = tid & 63, wave = tid >> 6;
  // in-block T1: suffix-scan ghist[b] (ping-pong, 10 rounds)
  __shared__ unsigned sa[2][NBINS];
  __shared__ int sT;
  for (int i = tid; i < NBINS; i += 256) sa[0][i] = ghist[b * NBINS + i];
  __syncthreads();
  int src = 0;
  for (int d = 1; d < NBINS; d <<= 1) {
    for (int i = tid; i < NBINS; i += 256)
      sa[src ^ 1][i] = sa[src][i] + ((i + d < NBINS) ? sa[src][i + d] : 0u);
    __syncthreads();
    src ^= 1;
  }
  for (int i = tid; i < NBINS; i += 256) {
    unsigned v = sa[src][i];
    unsigned nx = (i < NBINS - 1) ? sa[src][i + 1] : 0u;
    if (v >= PRE_NMS && nx < PRE_NMS) sT = i;
  }
  __syncthreads();
  int T = sT;
  if (slice == 0 && tid == 0) T1[b] = T;   // for refine_select
  int per = (A + NSLICE - 1) / NSLICE;
  int lo = slice * per, hi = min(lo + per, A);
  const float* sc = scores + (size_t)b * A;
  int cnt = 0;
  for (int i = lo + tid; i < hi; i += 256)
    cnt += ((int)(key_of(sc[i]) >> 22) >= T);
  int pfx = cnt;
  #pragma unroll
  for (int d = 1; d < 64; d <<= 1) {
    int t2 = __shfl_up(pfx, d, 64);
    if (lane >= d) pfx += t2;
  }
  __shared__ int s_wt[4];
  __shared__ int s_base;
  if (lane == 63) s_wt[wave] = pfx;
  __syncthreads();
  if (tid == 0) {
    int tot = s_wt[0] + s_wt[1] + s_wt[2] + s_wt[3];
    int acc = 0;
    #pragma unroll
    for (int w2 = 0; w2 < 4; ++w2) { int t3 = s_wt[w2]; s_wt[w2] = acc; acc += t3; }
    s_base = atomicAdd(&cand_cnt[b], tot);
  }
  __syncthreads();
  int my_off = s_base + s_wt[wave] + (pfx - cnt);
  u64* cb = cand + (size_t)b * CAP;
  for (int i = lo + tid; i < hi; i += 256) {
    unsigned k = key_of(sc[i]);
    if ((int)(k >> 22) >= T) {
      if (my_off < CAP) cb[my_off] = ((u64)k << 32) | (unsigned)(~i);
      my_off++;
    }
  }
}

// ---- K3: 20-bit threshold refinement, select ~2000-2048 cands (unsorted) --
__global__ __launch_bounds__(1024) void refine_select_kernel(
    const u64* __restrict__ cand, const int* __restrict__ cand_cnt,
    const int* __restrict__ T1,
    u64* __restrict__ gsel, int* __restrict__ sel_cnt) {
  int b = blockIdx.x, tid = threadIdx.x;
  int lane = tid & 63;
  __shared__ unsigned h2[NBINS];
  __shared__ unsigned tmp[NBINS];
  __shared__ int s_above, s_sel, s_T2;
  int n = min(cand_cnt[b], CAP);
  const u64* cb = cand + (size_t)b * CAP;
  h2[tid] = 0;
  if (tid == 0) { s_above = 0; s_sel = 0; }
  __syncthreads();
  int T1v = T1[b];
  int loc = 0;
  for (int i = tid; i < n; i += 1024) {
    unsigned k = (unsigned)(cb[i] >> 32);
    if ((int)(k >> 22) > T1v) loc++;
    else atomicAdd(&h2[(k >> 12) & 1023], 1u);
  }
  for (int d = 32; d; d >>= 1) loc += __shfl_down(loc, d, 64);
  if (lane == 0 && loc) atomicAdd(&s_above, loc);
  __syncthreads();
  unsigned v = h2[tid];
  for (int d = 1; d < NBINS; d <<= 1) {
    tmp[tid] = v;
    __syncthreads();
    if (tid + d < NBINS) v += tmp[tid + d];
    __syncthreads();
  }
  tmp[tid] = v;
  __syncthreads();
  int above = s_above;
  unsigned nextv = (tid < NBINS - 1) ? tmp[tid + 1] : 0u;
  if (above + (int)v >= PRE_NMS && above + (int)nextv < PRE_NMS) s_T2 = tid;
  __syncthreads();
  unsigned thresh20 = ((unsigned)T1v << 10) | (unsigned)s_T2;
  u64* gs = gsel + (size_t)b * SORTN;
  for (int i = tid; i < n; i += 1024) {
    u64 cv = cb[i];
    if ((unsigned)(cv >> 44) >= thresh20) {
      int pos = atomicAdd(&s_sel, 1);
      if (pos < SORTN) gs[pos] = cv;
    }
  }
  __syncthreads();
  if (tid == 0) sel_cnt[b] = min(s_sel, SORTN);
}

// ---- K4: parallel rank-count + fused decode -------------------------------
__global__ __launch_bounds__(256) void rank_decode_kernel(
    const u64* __restrict__ gsel, const int* __restrict__ sel_cnt,
    const float* __restrict__ deltas, const float* __restrict__ anchors, int A,
    float* __restrict__ boxes, float* __restrict__ topk_logit) {
  int b = blockIdx.x, ci = blockIdx.y;
  int tid = threadIdx.x;
  __shared__ u64 keys[SORTN];   // 16 KiB
  const u64* gs = gsel + (size_t)b * SORTN;
  int n = sel_cnt[b];           // in [2000, 2048]
  for (int i = tid; i < SORTN; i += 256)
    keys[i] = (i < n) ? gs[i] : 0ULL;
  __syncthreads();
  int i = ci * 256 + tid;
  u64 my = keys[i];
  int rank = 0;
  const ulonglong2* k2 = (const ulonglong2*)keys;
  #pragma unroll 4
  for (int j = 0; j < SORTN / 2; ++j) {
    ulonglong2 kk = k2[j];                 // uniform addr -> LDS broadcast
    rank += (kk.x > my) + (kk.y > my);
  }
  if (i < n && rank < PRE_NMS) {
    int a = (int)(~(unsigned)my);
    topk_logit[b * PRE_NMS + rank] = inv_key((unsigned)(my >> 32));
    const float CLIP = 4.135166556742356f;  // log(1000/16)
    float4 dl = ((const float4*)deltas)[(size_t)b * A + a];
    float4 an = ((const float4*)anchors)[a];
    float wa = __fsub_rn(an.z, an.x);
    float ha = __fsub_rn(an.w, an.y);
    float cxa = __fadd_rn(an.x, __fmul_rn(0.5f, wa));
    float cya = __fadd_rn(an.y, __fmul_rn(0.5f, ha));
    float dw = fminf(dl.z, CLIP), dh = fminf(dl.w, CLIP);
    float cx = __fadd_rn(__fmul_rn(dl.x, wa), cxa);
    float cy = __fadd_rn(__fmul_rn(dl.y, ha), cya);
    float w2 = __fmul_rn((float)exp((double)dw), wa);
    float h2f = __fmul_rn((float)exp((double)dh), ha);
    float x1 = __fsub_rn(cx, __fmul_rn(0.5f, w2));
    float y1 = __fsub_rn(cy, __fmul_rn(0.5f, h2f));
    float x2 = __fadd_rn(cx, __fmul_rn(0.5f, w2));
    float y2 = __fadd_rn(cy, __fmul_rn(0.5f, h2f));
    x1 = fminf(fmaxf(x1, 0.f), IMGSZ);
    y1 = fminf(fmaxf(y1, 0.f), IMGSZ);
    x2 = fminf(fmaxf(x2, 0.f), IMGSZ);
    y2 = fminf(fmaxf(y2, 0.f), IMGSZ);
    ((float4*)boxes)[(size_t)b * PRE_NMS + rank] = make_float4(x1, y1, x2, y2);
  }
}

// ---- K5: IoU tiles, one wave per 64x64 upper-triangle tile ----------------
__global__ __launch_bounds__(64) void iou_tile(
    const float* __restrict__ boxes, u64* __restrict__ maskT) {
  int k = blockIdx.x;       // 0..527 -> (ti <= wj) pair
  int b = blockIdx.y;
  int wj = (int)((sqrtf(8.0f * k + 1.0f) - 1.0f) * 0.5f);
  while ((wj + 1) * (wj + 2) / 2 <= k) ++wj;
  while (wj * (wj + 1) / 2 > k) --wj;
  int ti = k - wj * (wj + 1) / 2;
  int lane = threadIdx.x;
  int i = ti * 64 + lane;
  const float4* bb = (const float4*)boxes + (size_t)b * PRE_NMS;
  __shared__ float4 sbox[64];
  int jg = wj * 64 + lane;
  sbox[lane] = bb[min(jg, PRE_NMS - 1)];
  float4 A4 = bb[min(i, PRE_NMS - 1)];
  __syncthreads();
  float area_a = __fmul_rn(__fsub_rn(A4.z, A4.x), __fsub_rn(A4.w, A4.y));
  u64 m = 0;
  #pragma unroll 8
  for (int jj = 0; jj < 64; ++jj) {
    float4 Bb = sbox[jj];                  // uniform address -> broadcast
    float area_b = __fmul_rn(__fsub_rn(Bb.z, Bb.x), __fsub_rn(Bb.w, Bb.y));
    float ltx = fmaxf(A4.x, Bb.x), lty = fmaxf(A4.y, Bb.y);
    float rbx = fminf(A4.z, Bb.z), rby = fminf(A4.w, Bb.w);
    float iw = fmaxf(__fsub_rn(rbx, ltx), 0.f);
    float ih = fmaxf(__fsub_rn(rby, lty), 0.f);
    float inter = __fmul_rn(iw, ih);
    float denom = __fadd_rn(__fsub_rn(__fadd_rn(area_a, area_b), inter), 1e-9f);
    float iou = inter / denom;
    int j = wj * 64 + jj;
    if (j > i && iou > IOU_T) m |= 1ULL << jj;
  }
  maskT[((size_t)b * NWORDS + wj) * MROWS + i] = m;   // coalesced
}

// ---- K6: NMS scan v7 — pipelined: phase2(c-1) overlaps phase1(c) ----------
// Triple-buffered LDS; ONE barrier per window. All keep-updates are LDS
// atomicAnd (commute). Coverage: word q->c applied at window q+1 (waves 1-3,
// q<=c-2) or window c-1 (wave 0, q=c-1) — always before window c reads it.
#define WSTRIDE 65
__global__ __launch_bounds__(256, 1) void nms_scan(
    const u64* __restrict__ maskT, const float* __restrict__ boxes,
    const float* __restrict__ logits, float* __restrict__ out) {
  int b = blockIdx.x;
  int tid = threadIdx.x;
  int wave = tid >> 6, lane = tid & 63;
  __shared__ u64 buf[3][NWORDS * WSTRIDE];   // 3 x 16.25 KiB
  __shared__ u64 s_keep[NWORDS];
  __shared__ u64 s_cur[2];
  if (tid < NWORDS) s_keep[tid] = (tid == NWORDS - 1) ? 0xFFFFULL : ~0ULL;
  const u64* mb = maskT + (size_t)b * NWORDS * MROWS;
  int w = tid >> 3;          // word 0..31
  int sub = tid & 7;         // rows sub*8 .. sub*8+7 of the chunk
  uint4 nx0, nx1, nx2, nx3;
  { // load + store chunk 0
    const uint4* src = (const uint4*)(mb + (size_t)w * MROWS + sub * 8);
    uint4 a0 = src[0], a1 = src[1], a2 = src[2], a3 = src[3];
    u64* dst = &buf[0][w * WSTRIDE + sub * 8];
    dst[0] = ((u64)a0.y << 32) | a0.x;  dst[1] = ((u64)a0.w << 32) | a0.z;
    dst[2] = ((u64)a1.y << 32) | a1.x;  dst[3] = ((u64)a1.w << 32) | a1.z;
    dst[4] = ((u64)a2.y << 32) | a2.x;  dst[5] = ((u64)a2.w << 32) | a2.z;
    dst[6] = ((u64)a3.y << 32) | a3.x;  dst[7] = ((u64)a3.w << 32) | a3.z;
  }
  if (w >= 1) { // prefetch chunk 1 (upper-triangle words only)
    const uint4* src = (const uint4*)(mb + (size_t)w * MROWS + 64 + sub * 8);
    nx0 = src[0]; nx1 = src[1]; nx2 = src[2]; nx3 = src[3];
  }
  __syncthreads();
  for (int c = 0; c < NWORDS; ++c) {
    // store chunk c+1 from prefetch regs (readers start next window)
    if (c + 1 < NWORDS && w >= c + 1) {
      u64* dst = &buf[(c + 1) % 3][w * WSTRIDE + sub * 8];
      dst[0] = ((u64)nx0.y << 32) | nx0.x;  dst[1] = ((u64)nx0.w << 32) | nx0.z;
      dst[2] = ((u64)nx1.y << 32) | nx1.x;  dst[3] = ((u64)nx1.w << 32) | nx1.z;
      dst[4] = ((u64)nx2.y << 32) | nx2.x;  dst[5] = ((u64)nx2.w << 32) | nx2.z;
      dst[6] = ((u64)nx3.y << 32) | nx3.x;  dst[7] = ((u64)nx3.w << 32) | nx3.z;
    }
    if (c + 2 < NWORDS && w >= c + 2) { // prefetch chunk c+2
      const uint4* src = (const uint4*)(mb + (size_t)w * MROWS + (c + 2) * 64 + sub * 8);
      nx0 = src[0]; nx1 = src[1]; nx2 = src[2]; nx3 = src[3];
    }
    if (wave == 0) {
      // phase 1: serial diagonal resolve (readlane -> SALU chain)
      u64 diag = buf[c % 3][c * WSTRIDE + lane];
      unsigned dlo = (unsigned)diag, dhi = (unsigned)(diag >> 32);
      u64 k0 = s_keep[c];
      unsigned clo = __builtin_amdgcn_readfirstlane((unsigned)k0);
      unsigned chi = __builtin_amdgcn_readfirstlane((unsigned)(k0 >> 32));
      #pragma unroll
      for (int bb = 0; bb < 32; ++bb) {
        unsigned rlo = __builtin_amdgcn_readlane(dlo, bb);
        unsigned rhi = __builtin_amdgcn_readlane(dhi, bb);
        unsigned msk = 0u - ((clo >> bb) & 1u);
        clo &= ~(rlo & msk);
        chi &= ~(rhi & msk);
      }
      #pragma unroll
      for (int bb = 0; bb < 32; ++bb) {
        unsigned rlo = __builtin_amdgcn_readlane(dlo, bb + 32);
        unsigned rhi = __builtin_amdgcn_readlane(dhi, bb + 32);
        unsigned msk = 0u - ((chi >> bb) & 1u);
        clo &= ~(rlo & msk);
        chi &= ~(rhi & msk);
      }
      u64 cur = ((u64)chi << 32) | clo;
      if (lane == 0) { s_keep[c] = cur; s_cur[c & 1] = cur; }
      // apply word c -> word c+1 now (masked OR butterfly)
      if (c + 1 < NWORDS) {
        u64 row = buf[c % 3][(c + 1) * WSTRIDE + lane];
        u64 bit = (cur >> lane) & 1ULL;
        u64 v = row & (0ULL - bit);
        v |= __shfl_xor(v, 1, 64);
        v |= __shfl_xor(v, 2, 64);
        v |= __shfl_xor(v, 4, 64);
        v |= __shfl_xor(v, 8, 64);
        v |= __shfl_xor(v, 16, 64);
        v |= __shfl_xor(v, 32, 64);
        if (lane == 0 && v) atomicAnd(&s_keep[c + 1], ~v);
      }
    } else if (c >= 1) {
      // phase 2 (pipelined): word c-1 -> words >= c+1 on chunk c-1's buffer
      u64 kept = s_cur[(c - 1) & 1];
      int g = lane >> 3, s = lane & 7;
      const u64* bbuf = &buf[(c - 1) % 3][0];
      for (int idx = (wave - 1) + 3 * g; idx < NWORDS - 1 - c; idx += 24) {
        int w2 = c + 1 + idx;
        u64 v = 0;
        #pragma unroll
        for (int k = 0; k < 8; ++k) {
          int r = s + 8 * k;
          u64 bit = (kept >> r) & 1ULL;
          v |= bbuf[w2 * WSTRIDE + r] & (0ULL - bit);
        }
        v |= __shfl_xor(v, 1, 64);
        v |= __shfl_xor(v, 2, 64);
        v |= __shfl_xor(v, 4, 64);
        if (s == 0 && v) atomicAnd(&s_keep[w2], ~v);
      }
    }
    __syncthreads();                     // single barrier per window
  }
  // fused emit: rank kept boxes, write [box, sigmoid]; zero rows >= total
  __shared__ int pre[NWORDS];
  __shared__ int s_tot;
  if (tid == 0) {
    int acc = 0;
    for (int ww = 0; ww < NWORDS; ++ww) {
      pre[ww] = acc;
      acc += __popcll(s_keep[ww]);
    }
    s_tot = acc;
  }
  __syncthreads();
  const float* lg_b = logits + b * PRE_NMS;
  const float4* bx_b = (const float4*)boxes + (size_t)b * PRE_NMS;
  for (int i = tid; i < PRE_NMS; i += 256) {
    u64 wv = s_keep[i >> 6];
    if ((wv >> (i & 63)) & 1) {
      int rank = pre[i >> 6] + __popcll(wv & ((1ULL << (i & 63)) - 1ULL));
      if (rank < POST_NMS) {
        float4 bx = bx_b[i];
        float lg = lg_b[i];
        float e = (float)exp(-(double)lg);
        float pp = 1.0f / (1.0f + e);
        float* o = out + ((size_t)b * POST_NMS + rank) * 5;
        o[0] = bx.x; o[1] = bx.y; o[2] = bx.z; o[3] = bx.w; o[4] = pp;
      }
    }
  }
  int tot = s_tot;
  for (int j = tid; j < POST_NMS; j += 256) {
    if (j >= tot) {
      float* o = out + ((size_t)b * POST_NMS + j) * 5;
      o[0] = 0.f; o[1] = 0.f; o[2] = 0.f; o[3] = 0.f; o[4] = 0.f;
    }
  }
}

extern "C" void kernel_launch(void* const* d_in, const int* in_sizes, int n_in,
                              void* d_out, int out_size, void* d_ws, size_t ws_size,
                              hipStream_t stream) {
  const float* scores  = (const float*)d_in[0];
  const float* deltas  = (const float*)d_in[1];
  const float* anchors = (const float*)d_in[2];
  int A = in_sizes[2] / 4;          // 159882
  int B = in_sizes[0] / A;          // 16

  char* ws = (char*)d_ws;
  size_t off = 0;
  auto alloc = [&](size_t bytes) {
    void* p = ws + off;
    off += (bytes + 255) & ~(size_t)255;
    return p;
  };
  // zeroed region: ghist | cand_cnt
  unsigned* ghist    = (unsigned*)alloc((size_t)B * NBINS * 4);
  int*      cand_cnt = (int*)alloc((size_t)B * 4);
  size_t zero_bytes = off;
  int*      T1       = (int*)alloc((size_t)B * 4);
  u64*      cand     = (u64*)alloc((size_t)B * CAP * 8);
  u64*      gsel     = (u64*)alloc((size_t)B * SORTN * 8);
  int*      sel_cnt  = (int*)alloc((size_t)B * 4);
  float*    topk_lg  = (float*)alloc((size_t)B * PRE_NMS * 4);
  float*    boxes    = (float*)alloc((size_t)B * PRE_NMS * 16);
  u64*      maskT    = (u64*)alloc((size_t)B * NWORDS * MROWS * 8);

  hipMemsetAsync(ws, 0, zero_bytes, stream);

  hist_kernel<<<dim3(B, NSLICE), 256, 0, stream>>>(scores, A, ghist);
  compact_kernel<<<dim3(B, NSLICE), 256, 0, stream>>>(scores, A, ghist, cand, cand_cnt, T1);
  refine_select_kernel<<<B, 1024, 0, stream>>>(cand, cand_cnt, T1, gsel, sel_cnt);
  rank_decode_kernel<<<dim3(B, SORTN / 256), 256, 0, stream>>>(
      gsel, sel_cnt, deltas, anchors, A, boxes, topk_lg);
  int ntiles = NWORDS * (NWORDS + 1) / 2;   // 528 upper-triangle tiles
  iou_tile<<<dim3(ntiles, B), 64, 0, stream>>>(boxes, maskT);
  nms_scan<<<B, 256, 0, stream>>>(maskT, boxes, topk_lg, (float*)d_out);
}